// Round 1
// baseline (402.439 us; speedup 1.0000x reference)
//
#include <hip/hip_runtime.h>
#include <stdint.h>
#include <stddef.h>

#define M_DIM 8192
#define N_DIM 4096
#define K_DIM 4096

#define BM 128
#define BN 128
#define BK 128   // int8: 128 rows x 128 bytes = 16 KiB per operand tile

typedef int i32x4 __attribute__((ext_vector_type(4)));

__device__ __forceinline__ void async_load16(void* lds, const void* g) {
  __builtin_amdgcn_global_load_lds(
      (const __attribute__((address_space(1))) void*)g,
      (__attribute__((address_space(3))) void*)lds,
      16, 0, 0);
}

// Per-token (row) symmetric int8 quantization of x.
// One block per row of 4096 fp32. s_r = rowmax/127; xq = rint(x/s_r).
// R5: fully lane-contiguous access. Thread t handles float4 chunks
// {r*256 + t} (consecutive lanes -> consecutive 16B), fixing the old
// 64B-lane-stride sectored pattern (4x VMEM transactions).
__global__ void quant_x_kernel(const float* __restrict__ x,
                               signed char* __restrict__ xq,
                               float* __restrict__ xs) {
  const int row = blockIdx.x;
  const float4* xr = (const float4*)(x + (size_t)row * K_DIM);
  const int t = threadIdx.x;
  float4 v[4];
  float m = 0.f;
#pragma unroll
  for (int r = 0; r < 4; ++r) {
    v[r] = xr[r * 256 + t];                       // coalesced 16B/lane
    m = fmaxf(m, fmaxf(fmaxf(fabsf(v[r].x), fabsf(v[r].y)),
                       fmaxf(fabsf(v[r].z), fabsf(v[r].w))));
  }
#pragma unroll
  for (int off = 32; off > 0; off >>= 1)
    m = fmaxf(m, __shfl_down(m, off, 64));
  __shared__ float wmax[4];
  if ((t & 63) == 0) wmax[t >> 6] = m;
  __syncthreads();
  float rowmax = fmaxf(fmaxf(wmax[0], wmax[1]), fmaxf(wmax[2], wmax[3]));
  float inv = rowmax > 0.f ? 127.0f / rowmax : 0.f;
  if (t == 0) xs[row] = rowmax > 0.f ? rowmax * (1.0f / 127.0f) : 0.f;
  uint* oq = (uint*)(xq + (size_t)row * K_DIM);
#pragma unroll
  for (int r = 0; r < 4; ++r) {
    union { signed char c[4]; uint u; } o;
    o.c[0] = (signed char)(int)rintf(v[r].x * inv);
    o.c[1] = (signed char)(int)rintf(v[r].y * inv);
    o.c[2] = (signed char)(int)rintf(v[r].z * inv);
    o.c[3] = (signed char)(int)rintf(v[r].w * inv);
    oq[r * 256 + t] = o.u;                        // coalesced 4B/lane
  }
}

// W int32 [-127,127] -> int8 (exact pack).
// R5: lane-contiguous. Thread t handles int4 chunks {blk*1024 + r*256 + t}:
// consecutive lanes read consecutive 16B, write consecutive 4B.
__global__ void pack_w_kernel(const int* __restrict__ w, signed char* __restrict__ wp) {
  const int4* wi = (const int4*)w;
  uint* wo = (uint*)wp;
  size_t base = (size_t)blockIdx.x * 1024 + threadIdx.x;   // int4-chunk index
#pragma unroll
  for (int r = 0; r < 4; ++r) {
    int4 a = wi[base + r * 256];
    union { signed char c[4]; uint u; } o;
    o.c[0] = (signed char)a.x; o.c[1] = (signed char)a.y;
    o.c[2] = (signed char)a.z; o.c[3] = (signed char)a.w;
    wo[base + r * 256] = o.u;
  }
}

// C[M,N] = sum_k Aq[m,k]*Bq[n,k] * xs[m] * scaler[n], int8 MFMA 16x16x64.
// Aq,Bq int8 K-contiguous. 128x128 tile, BK=128, 4 waves (2x2 of 64x64).
// Both operands: 128 rows x 8 chunks(16B), XOR chunk swizzle (measured 0
// conflicts R2-R4 with identical geometry). A/B frag: 16 consecutive int8
// per lane, k=(lane>>4)*16+j (extrapolated from m89-verified bf16 pattern;
// identical 4-VGPR register shape). C/D layout dtype-independent (m121-m128).
// UNCHANGED in R5 (control for the aux-kernel coalescing change).
__global__ __launch_bounds__(256, 2) void gemm_i8(
    const signed char* __restrict__ Aq, const signed char* __restrict__ Bq,
    const float* __restrict__ xs, const float* __restrict__ scaler,
    float* __restrict__ C) {
  __shared__ __align__(16) uint8_t sA[BM * BK];  // 16 KiB
  __shared__ __align__(16) uint8_t sB[BN * BK];  // 16 KiB

  // XCD-grouped mapping (neutral R4, harmless; keeps B slabs L2-resident).
  const int bid  = blockIdx.x;
  const int xcd  = bid & 7;
  const int slot = bid >> 3;
  const int tile_n = (xcd * 4 + (slot & 3)) * BN;
  const int tile_m = (slot >> 2) * BM;

  const int w    = threadIdx.x >> 6;
  const int lane = threadIdx.x & 63;
  const int q    = lane >> 4;
  const int m16  = lane & 15;
  const int wrow = (w >> 1) * 64;
  const int wcol = (w & 1) * 64;

  i32x4 acc[4][4];
#pragma unroll
  for (int i = 0; i < 4; ++i)
#pragma unroll
    for (int j = 0; j < 4; ++j)
      acc[i][j] = (i32x4){0, 0, 0, 0};

  for (int kt = 0; kt < K_DIM; kt += BK) {
    // Stage A and B: 1024 16B-chunks each, 4 rounds x 4 waves x 64 lanes.
    // Slot g holds (r = g>>3, c = (g&7) ^ (r&7)); lds addr = wave-uniform
    // base + lane*16 (global_load_lds constraint).
#pragma unroll
    for (int p = 0; p < 4; ++p) {
      int g = ((p * 4 + w) << 6) + lane;
      int r = g >> 3;
      int c = (g & 7) ^ (r & 7);
      async_load16(sA + (size_t)g * 16,
                   Aq + (size_t)(tile_m + r) * K_DIM + kt + c * 16);
    }
#pragma unroll
    for (int p = 0; p < 4; ++p) {
      int g = ((p * 4 + w) << 6) + lane;
      int r = g >> 3;
      int c = (g & 7) ^ (r & 7);
      async_load16(sB + (size_t)g * 16,
                   Bq + (size_t)(tile_n + r) * K_DIM + kt + c * 16);
    }
    __syncthreads();

#pragma unroll
    for (int ks = 0; ks < 2; ++ks) {
      const int ck = (ks << 2) + q;   // chunk index 0..7 = K bytes [ck*16, +16)
      i32x4 af[4], bfr[4];
#pragma unroll
      for (int t = 0; t < 4; ++t) {
        int ra = wrow + t * 16 + m16;
        af[t] = *(const i32x4*)(sA + (size_t)(((ra << 3) + (ck ^ (ra & 7))) << 4));
        int rb = wcol + t * 16 + m16;
        bfr[t] = *(const i32x4*)(sB + (size_t)(((rb << 3) + (ck ^ (rb & 7))) << 4));
      }
#pragma unroll
      for (int i = 0; i < 4; ++i)
#pragma unroll
        for (int j = 0; j < 4; ++j)
          acc[i][j] = __builtin_amdgcn_mfma_i32_16x16x64_i8(
              af[i], bfr[j], acc[i][j], 0, 0, 0);
    }
    __syncthreads();
  }

  // Epilogue: C/D col=lane&15, row=(lane>>4)*4+reg (verified layout).
  float rs[4][4];
#pragma unroll
  for (int i = 0; i < 4; ++i)
#pragma unroll
    for (int r = 0; r < 4; ++r)
      rs[i][r] = xs[tile_m + wrow + i * 16 + q * 4 + r];
#pragma unroll
  for (int j = 0; j < 4; ++j) {
    int col = tile_n + wcol + j * 16 + m16;
    float s = scaler[col];
#pragma unroll
    for (int i = 0; i < 4; ++i) {
      int row0 = tile_m + wrow + i * 16 + q * 4;
#pragma unroll
      for (int r = 0; r < 4; ++r)
        C[(size_t)(row0 + r) * N_DIM + col] = (float)acc[i][j][r] * rs[i][r] * s;
    }
  }
}

// Correct-but-slow insurance if ws_size is too small.
__global__ void fallback_kernel(const float* __restrict__ x,
                                const int* __restrict__ wq,
                                const float* __restrict__ s,
                                float* __restrict__ out) {
  size_t idx = (size_t)blockIdx.x * blockDim.x + threadIdx.x;
  int m = (int)(idx / N_DIM), n = (int)(idx % N_DIM);
  const float* xr = x + (size_t)m * K_DIM;
  const int* wr = wq + (size_t)n * K_DIM;
  float acc = 0.f;
  for (int k = 0; k < K_DIM; ++k) acc += xr[k] * (float)wr[k];
  out[idx] = acc * s[n];
}

extern "C" void kernel_launch(void* const* d_in, const int* in_sizes, int n_in,
                              void* d_out, int out_size, void* d_ws, size_t ws_size,
                              hipStream_t stream) {
  const float* x = (const float*)d_in[0];
  const int* wq = (const int*)d_in[1];   // int32 (verified R2)
  const float* sc = (const float*)d_in[2];
  float* out = (float*)d_out;

  const size_t nx = (size_t)M_DIM * K_DIM;   // 33,554,432
  const size_t nw = (size_t)N_DIM * K_DIM;   // 16,777,216
  const size_t off_xq = 32768;               // xs: 8192 floats
  const size_t off_wp = off_xq + nx;
  const size_t need = off_wp + nw;           // ~50.4 MB

  if (ws_size < need) {
    size_t total = (size_t)M_DIM * N_DIM;
    fallback_kernel<<<(int)(total / 256), 256, 0, stream>>>(x, wq, sc, out);
    return;
  }

  float* xs = (float*)d_ws;
  signed char* xq = (signed char*)d_ws + off_xq;
  signed char* wp = (signed char*)d_ws + off_wp;

  quant_x_kernel<<<M_DIM, 256, 0, stream>>>(x, xq, xs);
  // nw/4 int4-chunks, 1024 chunks per block -> 4096 blocks.
  pack_w_kernel<<<(int)(nw / 4 / 1024), 256, 0, stream>>>(wq, wp);

  gemm_i8<<<(N_DIM / BN) * (M_DIM / BM), 256, 0, stream>>>(xq, wp, xs, sc, out);
}

// Round 3
// 401.808 us; speedup vs baseline: 1.0016x; 1.0016x over previous
//
#include <hip/hip_runtime.h>
#include <stdint.h>
#include <stddef.h>

#define M_DIM 8192
#define N_DIM 4096
#define K_DIM 4096

#define BM 128
#define BN 128
#define BK 128   // int8: 128 rows x 128 bytes = 16 KiB per operand tile

typedef int i32x4 __attribute__((ext_vector_type(4)));

__device__ __forceinline__ void async_load16(void* lds, const void* g) {
  __builtin_amdgcn_global_load_lds(
      (const __attribute__((address_space(1))) void*)g,
      (__attribute__((address_space(3))) void*)lds,
      16, 0, 0);
}

// Per-token (row) symmetric int8 quantization of x. UNCHANGED from R5
// (lane-contiguous; control for the gemm dbuf change).
__global__ void quant_x_kernel(const float* __restrict__ x,
                               signed char* __restrict__ xq,
                               float* __restrict__ xs) {
  const int row = blockIdx.x;
  const float4* xr = (const float4*)(x + (size_t)row * K_DIM);
  const int t = threadIdx.x;
  float4 v[4];
  float m = 0.f;
#pragma unroll
  for (int r = 0; r < 4; ++r) {
    v[r] = xr[r * 256 + t];                       // coalesced 16B/lane
    m = fmaxf(m, fmaxf(fmaxf(fabsf(v[r].x), fabsf(v[r].y)),
                       fmaxf(fabsf(v[r].z), fabsf(v[r].w))));
  }
#pragma unroll
  for (int off = 32; off > 0; off >>= 1)
    m = fmaxf(m, __shfl_down(m, off, 64));
  __shared__ float wmax[4];
  if ((t & 63) == 0) wmax[t >> 6] = m;
  __syncthreads();
  float rowmax = fmaxf(fmaxf(wmax[0], wmax[1]), fmaxf(wmax[2], wmax[3]));
  float inv = rowmax > 0.f ? 127.0f / rowmax : 0.f;
  if (t == 0) xs[row] = rowmax > 0.f ? rowmax * (1.0f / 127.0f) : 0.f;
  uint* oq = (uint*)(xq + (size_t)row * K_DIM);
#pragma unroll
  for (int r = 0; r < 4; ++r) {
    union { signed char c[4]; uint u; } o;
    o.c[0] = (signed char)(int)rintf(v[r].x * inv);
    o.c[1] = (signed char)(int)rintf(v[r].y * inv);
    o.c[2] = (signed char)(int)rintf(v[r].z * inv);
    o.c[3] = (signed char)(int)rintf(v[r].w * inv);
    oq[r * 256 + t] = o.u;                        // coalesced 4B/lane
  }
}

// W int32 [-127,127] -> int8 (exact pack). UNCHANGED from R5.
__global__ void pack_w_kernel(const int* __restrict__ w, signed char* __restrict__ wp) {
  const int4* wi = (const int4*)w;
  uint* wo = (uint*)wp;
  size_t base = (size_t)blockIdx.x * 1024 + threadIdx.x;   // int4-chunk index
#pragma unroll
  for (int r = 0; r < 4; ++r) {
    int4 a = wi[base + r * 256];
    union { signed char c[4]; uint u; } o;
    o.c[0] = (signed char)a.x; o.c[1] = (signed char)a.y;
    o.c[2] = (signed char)a.z; o.c[3] = (signed char)a.w;
    wo[base + r * 256] = o.u;
  }
}

// C[M,N] = sum_k Aq[m,k]*Bq[n,k] * xs[m] * scaler[n], int8 MFMA 16x16x64.
// R6 (resubmitted R7 after infra failure): T3-minimum 2-phase double-buffer.
// Per K-step: issue next tile's global_load_lds FIRST (into buf^1), then
// ds_read+MFMA from buf[cur], then ONE __syncthreads() (compiler emits
// vmcnt(0) lgkmcnt(0) before s_barrier — exactly the drain the prefetch
// needs). Loads for t+1 stay in flight across the whole 32-MFMA compute
// of t. Race-free: stage and read touch disjoint buffers; the barrier
// orders the WAR on re-staging. Swizzle geometry unchanged (0 conflicts).
__global__ __launch_bounds__(256, 2) void gemm_i8(
    const signed char* __restrict__ Aq, const signed char* __restrict__ Bq,
    const float* __restrict__ xs, const float* __restrict__ scaler,
    float* __restrict__ C) {
  __shared__ __align__(16) uint8_t sA[2][BM * BK];  // 2 x 16 KiB
  __shared__ __align__(16) uint8_t sB[2][BN * BK];  // 2 x 16 KiB

  // XCD-grouped mapping (neutral R4, harmless; keeps B slabs L2-resident).
  const int bid  = blockIdx.x;
  const int xcd  = bid & 7;
  const int slot = bid >> 3;
  const int tile_n = (xcd * 4 + (slot & 3)) * BN;
  const int tile_m = (slot >> 2) * BM;

  const int w    = threadIdx.x >> 6;
  const int lane = threadIdx.x & 63;
  const int q    = lane >> 4;
  const int m16  = lane & 15;
  const int wrow = (w >> 1) * 64;
  const int wcol = (w & 1) * 64;

  // Per-thread staging slots are kt-invariant: precompute LDS offset and
  // global row/col-chunk. Slot g holds (r = g>>3, c = (g&7) ^ (r&7));
  // lds addr = wave-uniform base + lane*16 (global_load_lds constraint).
  int g_off[4];      // byte offset into sA/sB buffer
  size_t a_off[4];   // byte offset into Aq (minus kt)
  size_t b_off[4];   // byte offset into Bq (minus kt)
#pragma unroll
  for (int p = 0; p < 4; ++p) {
    int g = ((p * 4 + w) << 6) + lane;
    int r = g >> 3;
    int c = (g & 7) ^ (r & 7);
    g_off[p] = g * 16;
    a_off[p] = (size_t)(tile_m + r) * K_DIM + c * 16;
    b_off[p] = (size_t)(tile_n + r) * K_DIM + c * 16;
  }

  i32x4 acc[4][4];
#pragma unroll
  for (int i = 0; i < 4; ++i)
#pragma unroll
    for (int j = 0; j < 4; ++j)
      acc[i][j] = (i32x4){0, 0, 0, 0};

  // Prologue: stage kt=0 into buffer 0.
#pragma unroll
  for (int p = 0; p < 4; ++p) {
    async_load16(sA[0] + g_off[p], Aq + a_off[p]);
    async_load16(sB[0] + g_off[p], Bq + b_off[p]);
  }
  __syncthreads();   // vmcnt(0): buf0 ready

  int cur = 0;
  for (int kt = 0; kt < K_DIM; kt += BK) {
    // Phase 1: issue next tile's loads into buf^1 (stay in flight).
    if (kt + BK < K_DIM) {
      const uint8_t* nA = (const uint8_t*)Aq + (kt + BK);
      const uint8_t* nB = (const uint8_t*)Bq + (kt + BK);
#pragma unroll
      for (int p = 0; p < 4; ++p) {
        async_load16(sA[cur ^ 1] + g_off[p], nA + a_off[p]);
        async_load16(sB[cur ^ 1] + g_off[p], nB + b_off[p]);
      }
    }

    // Phase 2: compute from buf[cur] (lgkm-only; overlaps the vmem above).
    const uint8_t* cA = sA[cur];
    const uint8_t* cB = sB[cur];
#pragma unroll
    for (int ks = 0; ks < 2; ++ks) {
      const int ck = (ks << 2) + q;   // chunk index 0..7 = K bytes [ck*16, +16)
      i32x4 af[4], bfr[4];
#pragma unroll
      for (int t = 0; t < 4; ++t) {
        int ra = wrow + t * 16 + m16;
        af[t] = *(const i32x4*)(cA + (size_t)(((ra << 3) + (ck ^ (ra & 7))) << 4));
        int rb = wcol + t * 16 + m16;
        bfr[t] = *(const i32x4*)(cB + (size_t)(((rb << 3) + (ck ^ (rb & 7))) << 4));
      }
#pragma unroll
      for (int i = 0; i < 4; ++i)
#pragma unroll
        for (int j = 0; j < 4; ++j)
          acc[i][j] = __builtin_amdgcn_mfma_i32_16x16x64_i8(
              af[i], bfr[j], acc[i][j], 0, 0, 0);
    }

    // One barrier per K-step: drains this step's prefetch (vmcnt(0)) and
    // all waves' LDS reads (lgkmcnt(0)), then buf^1 becomes current.
    __syncthreads();
    cur ^= 1;
  }

  // Epilogue: C/D col=lane&15, row=(lane>>4)*4+reg (verified layout).
  float rs[4][4];
#pragma unroll
  for (int i = 0; i < 4; ++i)
#pragma unroll
    for (int r = 0; r < 4; ++r)
      rs[i][r] = xs[tile_m + wrow + i * 16 + q * 4 + r];
#pragma unroll
  for (int j = 0; j < 4; ++j) {
    int col = tile_n + wcol + j * 16 + m16;
    float s = scaler[col];
#pragma unroll
    for (int i = 0; i < 4; ++i) {
      int row0 = tile_m + wrow + i * 16 + q * 4;
#pragma unroll
      for (int r = 0; r < 4; ++r)
        C[(size_t)(row0 + r) * N_DIM + col] = (float)acc[i][j][r] * rs[i][r] * s;
    }
  }
}

// Correct-but-slow insurance if ws_size is too small.
__global__ void fallback_kernel(const float* __restrict__ x,
                                const int* __restrict__ wq,
                                const float* __restrict__ s,
                                float* __restrict__ out) {
  size_t idx = (size_t)blockIdx.x * blockDim.x + threadIdx.x;
  int m = (int)(idx / N_DIM), n = (int)(idx % N_DIM);
  const float* xr = x + (size_t)m * K_DIM;
  const int* wr = wq + (size_t)n * K_DIM;
  float acc = 0.f;
  for (int k = 0; k < K_DIM; ++k) acc += xr[k] * (float)wr[k];
  out[idx] = acc * s[n];
}

extern "C" void kernel_launch(void* const* d_in, const int* in_sizes, int n_in,
                              void* d_out, int out_size, void* d_ws, size_t ws_size,
                              hipStream_t stream) {
  const float* x = (const float*)d_in[0];
  const int* wq = (const int*)d_in[1];   // int32 (verified R2)
  const float* sc = (const float*)d_in[2];
  float* out = (float*)d_out;

  const size_t nx = (size_t)M_DIM * K_DIM;   // 33,554,432
  const size_t nw = (size_t)N_DIM * K_DIM;   // 16,777,216
  const size_t off_xq = 32768;               // xs: 8192 floats
  const size_t off_wp = off_xq + nx;
  const size_t need = off_wp + nw;           // ~50.4 MB

  if (ws_size < need) {
    size_t total = (size_t)M_DIM * N_DIM;
    fallback_kernel<<<(int)(total / 256), 256, 0, stream>>>(x, wq, sc, out);
    return;
  }

  float* xs = (float*)d_ws;
  signed char* xq = (signed char*)d_ws + off_xq;
  signed char* wp = (signed char*)d_ws + off_wp;

  quant_x_kernel<<<M_DIM, 256, 0, stream>>>(x, xq, xs);
  // nw/4 int4-chunks, 1024 chunks per block -> 4096 blocks.
  pack_w_kernel<<<(int)(nw / 4 / 1024), 256, 0, stream>>>(wq, wp);

  gemm_i8<<<(N_DIM / BN) * (M_DIM / BM), 256, 0, stream>>>(xq, wp, xs, sc, out);
}